// Round 15
// baseline (218.028 us; speedup 1.0000x reference)
//
#include <hip/hip_runtime.h>
#include <hip/hip_cooperative_groups.h>

namespace cg = cooperative_groups;

// EdgeEmbedding: B=8, L=256, A=15, K=9, EDGE_SIZE=16.
// Cooperative single-dispatch (GRID=512, 2 blocks/CU co-residency margin)
// with deterministic fallback to the proven R12 two-kernel pair if the
// cooperative launch is rejected (R14: 1024-block coop launch did not
// execute — suspected co-residency rejection). Both paths share the same
// __device__ bodies => bit-identical math => absmax 37 either way.
//
// Output layout (all float32, concatenated flat):
//   [0,      30720)  block_id   = i/15
//   [30720,  32768)  batch_id   = i/256
//   [32768, 106496)  edges [2][36864]   (row0 src, row1 dst; intra then inter)
//   [106496,696320)  edge_attr [36864][16]

#define BB   8
#define LL   256
#define AA   15
#define KK   9

#define O_BATCH   30720
#define O_EDGES   32768
#define NE_HALF   18432   // B*L*K
#define NE        36864
#define O_ATTR    106496
#define N_FILL    622592  // 32768 + 589824 flat fill elements
#define DELTA     0.005f
#define EPS2      2e-3
#define HBASE     448     // (0x38000000 >> 21)
#define NBIN      128
#define MAXM      128

#define TW        16      // tile width
#define NTILE     136     // 16*17/2 triangular tiles
#define NDIST     1088    // BB * NTILE
#define GRID      512

// ---------------------------------------------------------------------------
// Shared bodies (used by BOTH cooperative and fallback paths).
// ---------------------------------------------------------------------------
struct SelSh {
    double dAi[AA * 3];
    double dX2i[AA];
    int    sHist[2 * NBIN];
    int    sList[MAXM];    // (cand<<1)|class
    double sVal[MAXM];     // key: promoted f32 or refined f64
    int    sRList[MAXM];
    int    sCnt, sRCnt;
};

__device__ __forceinline__ void dist_tile(
    const float* __restrict__ pos, float* __restrict__ D,
    int b, int t, float4 sI[AA][TW], float4 sJ[AA][TW])
{
    const int tid = threadIdx.x;
    // decode triangular index: off(r) = r*(33-r)/2
    int ti = (int)((33.0f - sqrtf(1089.0f - 8.0f * (float)t)) * 0.5f);
    while (ti * (33 - ti) / 2 > t) --ti;
    while ((ti + 1) * (32 - ti) / 2 <= t) ++ti;
    const int tj = ti + (t - ti * (33 - ti) / 2);
    const int I0 = ti * TW, J0 = tj * TW;

    if (tid < 240) {                 // 240 atoms per side
        const int bl = tid / AA, a = tid - bl * AA;
        {
            const float* p = pos + ((size_t)(b * LL + I0 + bl) * 45) + a * 3;
            float x = p[0], y = p[1], z = p[2];
            sI[a][bl] = make_float4(-2.f*x, -2.f*y, -2.f*z, x*x + y*y + z*z);
        }
        {
            const float* p = pos + ((size_t)(b * LL + J0 + bl) * 45) + a * 3;
            float x = p[0], y = p[1], z = p[2];
            sJ[a][bl] = make_float4(x, y, z, x*x + y*y + z*z);
        }
    }
    __syncthreads();

    const int il = tid >> 4, jl = tid & 15;
    float v = INFINITY;
    #pragma unroll 1
    for (int cb = 0; cb < AA; cb += 5) {     // chunked J keeps VGPR low
        float4 Jc[5]; float m[5];
        #pragma unroll
        for (int q = 0; q < 5; ++q) { Jc[q] = sJ[cb + q][jl]; m[q] = INFINITY; }
        #pragma unroll
        for (int a = 0; a < AA; ++a) {
            float4 A = sI[a][il];
            #pragma unroll
            for (int q = 0; q < 5; ++q) {
                float dp = fmaf(A.x, Jc[q].x,
                           fmaf(A.y, Jc[q].y,
                           fmaf(A.z, Jc[q].z, A.w)));
                m[q] = fminf(m[q], dp);
            }
        }
        #pragma unroll
        for (int q = 0; q < 5; ++q) v = fminf(v, m[q] + Jc[q].w);
    }
    v = fmaxf(v, 0.0f);

    if (ti != tj || jl >= il) {
        const int i = I0 + il, j = J0 + jl;
        const size_t base = ((size_t)b) << 16;
        D[base + (i << 8) + j] = v;
        D[base + (j << 8) + i] = v;
    }
}

__device__ __forceinline__ void select_row(
    const float* __restrict__ pos, const float* __restrict__ D,
    const int* __restrict__ frag, float* __restrict__ out,
    int blk, SelSh& sh)
{
    const int b = blk >> 8;
    const int i = blk & 255;
    const int j = threadIdx.x;

    if (j < AA) {
        const float* p = pos + (size_t)blk * 45 + j * 3;
        double dx = (double)p[0], dy = (double)p[1], dz = (double)p[2];
        sh.dAi[3*j] = dx; sh.dAi[3*j+1] = dy; sh.dAi[3*j+2] = dz;
        sh.dX2i[j] = dx*dx + dy*dy + dz*dz;
    }
    if (j < 2 * NBIN) sh.sHist[j] = 0;
    if (j == 255) sh.sCnt = 0;
    if (j == 254) sh.sRCnt = 0;

    const int ftj  = frag[b * LL + j];
    const int segj = (ftj == 2) ? 1 : ftj;
    const int fti  = frag[blk];
    const int segi = (fti == 2) ? 1 : fti;
    // class: 0 = intra (seg==segi, j!=i), 1 = inter, -1 = self
    const int cls  = (j == i) ? -1 : ((segj == segi) ? 0 : 1);

    const float d32 = D[(((size_t)b) << 16) + (i << 8) + j];
    __syncthreads();                 // hist zero visible

    if (cls >= 0) {
        int bin = (int)(__float_as_uint(d32) >> 21) - HBASE;
        bin = min(NBIN - 1, max(0, bin));
        atomicAdd(&sh.sHist[cls * NBIN + bin], 1);
    }
    __syncthreads();

    // every wave scans both classes (2 bins/lane); T in registers
    const int lane = j & 63;
    float T[2];
    #pragma unroll
    for (int cw = 0; cw < 2; ++cw) {
        int c0 = sh.sHist[cw * NBIN + 2*lane];
        int c1 = sh.sHist[cw * NBIN + 2*lane + 1];
        int s  = c0 + c1;
        int cum = s;
        #pragma unroll
        for (int off = 1; off < 64; off <<= 1) {
            int vv = __shfl_up(cum, off, 64);
            if (lane >= off) cum += vv;
        }
        unsigned long long msk = __ballot(cum >= KK);
        float t_ = INFINITY;
        if (msk != 0ull) {
            int f = __builtin_ctzll(msk);
            if (lane == f) {
                int before = cum - s;
                int bin = (before + c0 >= KK) ? 2*f : 2*f + 1;
                t_ = (bin >= NBIN - 1) ? INFINITY
                   : __uint_as_float((unsigned)(HBASE + bin + 1) << 21);
            }
            t_ = __shfl(t_, f, 64);
        }
        T[cw] = t_;
    }

    // mark superset; dense list + promoted-f32 keys
    if (cls >= 0 && d32 <= T[cls] + DELTA) {
        int p = atomicAdd(&sh.sCnt, 1);
        if (p < MAXM) {
            sh.sList[p] = (j << 1) | cls;
            sh.sVal[p]  = (double)d32;
        }
    }
    __syncthreads();
    const int cnt = min(sh.sCnt, MAXM);              // ~20-28

    // near-tie detection
    if (j < cnt) {
        double my = sh.sVal[j];
        int mycls = sh.sList[j] & 1;
        bool need = false;
        for (int u = 0; u < cnt; ++u) {
            if (u != j && (sh.sList[u] & 1) == mycls &&
                fabs(sh.sVal[u] - my) <= EPS2) need = true;
        }
        if (need) { int p = atomicAdd(&sh.sRCnt, 1); sh.sRList[p] = j; }
    }
    __syncthreads();

    // rare cooperative f64 refine (usually rcnt == 0)
    {
        const int rcnt = sh.sRCnt;
        const int wv = j >> 6;
        for (int base = 0; base < rcnt; base += 4) {
            int t = base + wv;
            double dmin = INFINITY;
            int slot = -1;
            if (t < rcnt) {
                slot = sh.sRList[t];
                int cand = sh.sList[slot] >> 1;
                const float* pc = pos + (size_t)(b * LL + cand) * 45;
                for (int p = lane; p < 225; p += 64) {
                    int a = p / 15, c = p - a * 15;
                    double cx = (double)pc[3*c], cy = (double)pc[3*c+1],
                           cz = (double)pc[3*c+2];
                    double dot = sh.dAi[3*a]*cx + sh.dAi[3*a+1]*cy
                               + sh.dAi[3*a+2]*cz;
                    double d2  = (sh.dX2i[a] + (cx*cx + cy*cy + cz*cz))
                               - 2.0 * dot;
                    dmin = fmin(dmin, d2);
                }
            }
            #pragma unroll
            for (int off = 1; off < 64; off <<= 1)
                dmin = fmin(dmin, __shfl_xor(dmin, off, 64));
            if (lane == 0 && t < rcnt) sh.sVal[slot] = fmax(dmin, 0.0);
        }
    }
    __syncthreads();

    // rank per slot; winners write ordered edge slots
    if (j < cnt) {
        int e   = sh.sList[j];
        int cnd = e >> 1, mycls = e & 1;
        double key = sh.sVal[j];
        int rr = 0;
        for (int u = 0; u < cnt; ++u) {
            int eu = sh.sList[u];
            if ((eu & 1) == mycls) {
                double ku = sh.sVal[u];
                int cu = eu >> 1;
                if (ku < key || (ku == key && cu < cnd)) ++rr;
            }
        }
        if (rr < KK) {
            int eo = (mycls == 0 ? 0 : NE_HALF) + blk * KK + rr;
            out[O_EDGES + eo]      = (float)blk;            // src
            out[O_EDGES + NE + eo] = (float)(b * LL + cnd); // dst
        }
    }
}

__device__ __forceinline__ void fill_slots(
    const float* __restrict__ emb, float* __restrict__ out,
    int base, int niter)
{
    const int tid = threadIdx.x;
    for (int k = 0; k < niter; ++k) {
        int gid = base + (k << 8) + tid;
        if (gid < 30720) {
            out[gid] = (float)(gid / AA);                    // block_id
        } else if (gid < 32768) {
            out[gid] = (float)((gid - 30720) >> 8);          // batch_id
        } else if (gid < N_FILL) {
            int a   = gid - 32768;                           // attr idx
            int sel = ((a >> 4) < NE_HALF) ? 0 : 16;
            out[O_ATTR + a] = emb[sel + (a & 15)];
        }
    }
}

// ---------------------------------------------------------------------------
// Cooperative single-dispatch path.  GRID=512 (2 blocks/CU worst case).
// ---------------------------------------------------------------------------
union CoopSh {
    struct { float4 sI[AA][TW]; float4 sJ[AA][TW]; } d;
    SelSh s;
};

__global__ __launch_bounds__(256) void edge_coop_kernel(
    const float* __restrict__ pos, const int* __restrict__ frag,
    const float* __restrict__ emb, float* __restrict__ D,
    float* __restrict__ out)
{
    cg::grid_group grid = cg::this_grid();
    const int bx = blockIdx.x;       // 0..511

    __shared__ CoopSh sh;

    // phase A: dist tiles (2-3 per block) + fills
    for (int t0 = bx; t0 < NDIST; t0 += GRID) {
        const int b = t0 / NTILE;
        dist_tile(pos, D, b, t0 - b * NTILE, sh.d.sI, sh.d.sJ);
        __syncthreads();             // protect sI/sJ reuse next trip
    }
    fill_slots(emb, out, bx * 1216, 5);   // 512*1216 >= 622592

    __threadfence();                 // D visible device-wide
    grid.sync();

    // phase B: 4 selection rows per block
    for (int r = 0; r < 4; ++r) {
        select_row(pos, D, frag, out, bx + r * GRID, sh.s);
        __syncthreads();             // protect shared reuse across rows
    }
}

// ---------------------------------------------------------------------------
// Fallback two-kernel path (R12, best passing: 90.1 us).
// ---------------------------------------------------------------------------
__global__ __launch_bounds__(256) void dist_kernel(
    const float* __restrict__ pos, float* __restrict__ D)
{
    __shared__ float4 sI[AA][TW];
    __shared__ float4 sJ[AA][TW];
    const int b = blockIdx.x / NTILE;
    dist_tile(pos, D, b, blockIdx.x - b * NTILE, sI, sJ);
}

__global__ __launch_bounds__(256) void select_kernel(
    const float* __restrict__ pos, const float* __restrict__ D,
    const int* __restrict__ frag, const float* __restrict__ emb,
    float* __restrict__ out)
{
    __shared__ SelSh sh;
    const int blk = blockIdx.x;
    // fills: 2048 blocks x 304 slots >= 622592
    fill_slots(emb, out, blk * 304, 2);
    select_row(pos, D, frag, out, blk, sh);
}

extern "C" void kernel_launch(void* const* d_in, const int* in_sizes, int n_in,
                              void* d_out, int out_size, void* d_ws, size_t ws_size,
                              hipStream_t stream) {
    const float* pos  = (const float*)d_in[0];   // pos_heavyatom [8,256,15,3] f32
    const int*   frag = (const int*)d_in[6];     // fragment_type [8,256] i32
    const float* emb  = (const float*)d_in[7];   // edge_emb [2,16] f32
    float* out = (float*)d_out;
    float* Dm  = (float*)d_ws;                   // [8,256,256] f32 = 2 MB

    void* args[] = { (void*)&pos, (void*)&frag, (void*)&emb,
                     (void*)&Dm, (void*)&out };
    hipError_t e = hipLaunchCooperativeKernel((const void*)edge_coop_kernel,
                                              dim3(GRID), dim3(256),
                                              args, 0, stream);
    if (e != hipSuccess) {
        (void)hipGetLastError();     // clear sticky error, take proven path
        dist_kernel<<<dim3(NDIST), dim3(256), 0, stream>>>(pos, Dm);
        select_kernel<<<dim3(BB * LL), dim3(256), 0, stream>>>(pos, Dm, frag,
                                                               emb, out);
    }
}

// Round 16
// 89.116 us; speedup vs baseline: 2.4466x; 2.4466x over previous
//
#include <hip/hip_runtime.h>

// EdgeEmbedding: B=8, L=256, A=15, K=9, EDGE_SIZE=16 — two kernels + 2MB d_ws.
// FINAL (R16 = revert to R12, the best passing configuration: 90.1 us).
//
// R15 post-mortem locked in the structure: cooperative single-dispatch
// (grid.sync) costs 130 us vs ~30 us for two plain dispatches — device-scope
// barriers across 8 XCDs are far more expensive than a dispatch boundary.
// R9-R11 (stall theories), R13 (fill migration) all neutral; the only wins
// were instruction-count cuts (R7 histogram, R12 symmetry). Remaining time:
// ~60 us harness poison/restore (268 MB fill at 83% HBM peak — its own
// roofline) + ~15-20 us dispatch ramps + ~6-10 us kernel work.
//
// Output layout (all float32, concatenated flat):
//   [0,      30720)  block_id   = i/15
//   [30720,  32768)  batch_id   = i/256
//   [32768, 106496)  edges [2][36864]   (row0 src, row1 dst; intra then inter)
//   [106496,696320)  edge_attr [36864][16]
//
//   K1: triangular 16x16 block-tiles (8 x 136 blocks); thread = one (i,j)
//       block pair; f32 min-atom-pair d^2 via {-2x,-2y,-2z,x2} packing
//       (3 fma + fmin per pair); written to both (i,j) and (j,i).
//   K2: per-row selection: read d^2 row (coalesced), 128-bin histogram
//       quantile -> threshold T >= 9th value; mark d <= T + DELTA
//       (DELTA = 5e-3 >= 8x the f32 error bound => marked set provably
//       contains the f64 top-9); lazy f64 refine only of same-class
//       near-ties within EPS2 = 2e-3 (usually none) on ORIGINAL pos —
//       bit-identical to the round-4 all-f64 kernel that matched the
//       oracle (absmax 37); rank among marked -> ordered edge writes.

#define BB   8
#define LL   256
#define AA   15
#define KK   9

#define O_BATCH   30720
#define O_EDGES   32768
#define NE_HALF   18432   // B*L*K
#define NE        36864
#define O_ATTR    106496
#define DELTA     0.005f
#define EPS2      2e-3
#define HBASE     448     // (0x38000000 >> 21)
#define NBIN      128
#define MAXM      128

#define TW        16      // tile width
#define NTILE     136     // 16*17/2 triangular tiles

// ---------------------------------------------------------------------------
// K1: block-pair distance tiles.  grid = B * 136.
// ---------------------------------------------------------------------------
__global__ __launch_bounds__(256) void dist_kernel(
    const float* __restrict__ pos,   // [B,L,A,3]
    float*       __restrict__ D)     // [B,L,L]
{
    const int bx = blockIdx.x;
    const int b  = bx / NTILE;
    const int t  = bx - b * NTILE;
    // decode triangular index: off(r) = r*(33-r)/2
    int ti = (int)((33.0f - sqrtf(1089.0f - 8.0f * (float)t)) * 0.5f);
    while (ti * (33 - ti) / 2 > t) --ti;
    while ((ti + 1) * (32 - ti) / 2 <= t) ++ti;
    const int tj = ti + (t - ti * (33 - ti) / 2);
    const int I0 = ti * TW, J0 = tj * TW;

    __shared__ float4 sI[AA][TW];    // i-side: {-2x,-2y,-2z,x2}
    __shared__ float4 sJ[AA][TW];    // j-side: { x,  y,  z, x2}

    const int tid = threadIdx.x;
    if (tid < 240) {                 // 240 atoms per side
        const int bl = tid / AA, a = tid - bl * AA;
        {
            const float* p = pos + ((size_t)(b * LL + I0 + bl) * 45) + a * 3;
            float x = p[0], y = p[1], z = p[2];
            sI[a][bl] = make_float4(-2.f*x, -2.f*y, -2.f*z, x*x + y*y + z*z);
        }
        {
            const float* p = pos + ((size_t)(b * LL + J0 + bl) * 45) + a * 3;
            float x = p[0], y = p[1], z = p[2];
            sJ[a][bl] = make_float4(x, y, z, x*x + y*y + z*z);
        }
    }
    __syncthreads();

    const int il = tid >> 4, jl = tid & 15;

    float4 J[AA];
    float  m[AA];
    #pragma unroll
    for (int c = 0; c < AA; ++c) { J[c] = sJ[c][jl]; m[c] = INFINITY; }

    #pragma unroll
    for (int a = 0; a < AA; ++a) {
        float4 A = sI[a][il];        // broadcast across 16 lanes
        #pragma unroll
        for (int c = 0; c < AA; ++c) {
            float dp = fmaf(A.x, J[c].x,
                       fmaf(A.y, J[c].y,
                       fmaf(A.z, J[c].z, A.w)));
            m[c] = fminf(m[c], dp);
        }
    }
    float v = INFINITY;
    #pragma unroll
    for (int c = 0; c < AA; ++c) v = fminf(v, m[c] + J[c].w);
    v = fmaxf(v, 0.0f);

    if (ti != tj || jl >= il) {
        const int i = I0 + il, j = J0 + jl;
        const size_t base = ((size_t)b) << 16;
        D[base + (i << 8) + j] = v;
        D[base + (j << 8) + i] = v;
    }
}

// ---------------------------------------------------------------------------
// K2: per-row selection + fills.  grid = B * L.
// ---------------------------------------------------------------------------
__global__ __launch_bounds__(256) void select_kernel(
    const float* __restrict__ pos,   // [B,L,A,3] (f64 refine path)
    const float* __restrict__ D,     // [B,L,L] f32 min d^2
    const int*   __restrict__ frag,  // [B,L]
    const float* __restrict__ emb,   // [2,16]
    float*       __restrict__ out)
{
    const int blk = blockIdx.x;      // = b*256 + i
    const int b   = blk >> 8;
    const int i   = blk & 255;
    const int j   = threadIdx.x;     // candidate dst block

    __shared__ double dAi[AA * 3];   // row-i coords (f64, refine path)
    __shared__ double dX2i[AA];
    __shared__ int    sHist[2 * NBIN];
    __shared__ int    sList[MAXM];   // (cand<<1)|class
    __shared__ double sVal[MAXM];    // key: promoted f32 or refined f64
    __shared__ int    sRList[MAXM];
    __shared__ int    sCnt, sRCnt;

    // ---- fused trivial fills ----
    if (j < AA)  out[blk * AA + j]  = (float)blk;     // block_id
    if (j == AA) out[O_BATCH + blk] = (float)b;       // batch_id
    {
        int idx = blk * 288 + j;
        out[O_ATTR + idx] = emb[(((idx >> 4) < NE_HALF) ? 0 : 16) + (idx & 15)];
        if (j < 32) {
            int idx2 = idx + 256;
            out[O_ATTR + idx2] = emb[(((idx2 >> 4) < NE_HALF) ? 0 : 16) + (idx2 & 15)];
        }
    }

    // ---- stage row-i atoms in f64 (refine path); zero hist ----
    if (j < AA) {
        const float* p = pos + (size_t)blk * 45 + j * 3;
        double dx = (double)p[0], dy = (double)p[1], dz = (double)p[2];
        dAi[3*j] = dx; dAi[3*j+1] = dy; dAi[3*j+2] = dz;
        dX2i[j] = dx*dx + dy*dy + dz*dz;
    }
    if (j < 2 * NBIN) sHist[j] = 0;
    if (j == 255) sCnt = 0;
    if (j == 254) sRCnt = 0;

    const int ftj  = frag[b * LL + j];
    const int segj = (ftj == 2) ? 1 : ftj;
    const int fti  = frag[blk];
    const int segi = (fti == 2) ? 1 : fti;
    // class: 0 = intra (seg==segi, j!=i), 1 = inter, -1 = self
    const int cls  = (j == i) ? -1 : ((segj == segi) ? 0 : 1);

    // ---- read d^2 from matrix (coalesced) ----
    const float d32 = D[(((size_t)b) << 16) + (i << 8) + j];
    __syncthreads();                                  // hist zero visible

    // ---- histogram (bits>>21 monotone for d32 >= 0) ----
    if (cls >= 0) {
        int bin = (int)(__float_as_uint(d32) >> 21) - HBASE;
        bin = min(NBIN - 1, max(0, bin));
        atomicAdd(&sHist[cls * NBIN + bin], 1);
    }
    __syncthreads();

    // ---- every wave scans both classes (2 bins/lane), T in registers ----
    const int lane = j & 63;
    float T[2];
    #pragma unroll
    for (int cw = 0; cw < 2; ++cw) {
        int c0 = sHist[cw * NBIN + 2*lane];
        int c1 = sHist[cw * NBIN + 2*lane + 1];
        int s  = c0 + c1;
        int cum = s;
        #pragma unroll
        for (int off = 1; off < 64; off <<= 1) {
            int v = __shfl_up(cum, off, 64);
            if (lane >= off) cum += v;
        }
        unsigned long long msk = __ballot(cum >= KK);
        float t_ = INFINITY;
        if (msk != 0ull) {
            int f = __builtin_ctzll(msk);
            if (lane == f) {
                int before = cum - s;
                int bin = (before + c0 >= KK) ? 2*f : 2*f + 1;
                t_ = (bin >= NBIN - 1) ? INFINITY
                   : __uint_as_float((unsigned)(HBASE + bin + 1) << 21);
            }
            t_ = __shfl(t_, f, 64);
        }
        T[cw] = t_;
    }

    // ---- mark superset; dense list + promoted-f32 keys ----
    if (cls >= 0 && d32 <= T[cls] + DELTA) {
        int p = atomicAdd(&sCnt, 1);
        if (p < MAXM) {
            sList[p] = (j << 1) | cls;
            sVal[p]  = (double)d32;
        }
    }
    __syncthreads();
    const int cnt = min(sCnt, MAXM);                  // ~20-28

    // ---- near-tie detection ----
    if (j < cnt) {
        double my = sVal[j];
        int mycls = sList[j] & 1;
        bool need = false;
        for (int u = 0; u < cnt; ++u) {
            if (u != j && (sList[u] & 1) == mycls &&
                fabs(sVal[u] - my) <= EPS2) need = true;
        }
        if (need) { int p = atomicAdd(&sRCnt, 1); sRList[p] = j; }
    }
    __syncthreads();

    // ---- rare cooperative f64 refine (usually rcnt == 0) ----
    {
        const int rcnt = sRCnt;
        const int wv = j >> 6;
        for (int base = 0; base < rcnt; base += 4) {
            int t = base + wv;
            double dmin = INFINITY;
            int slot = -1;
            if (t < rcnt) {
                slot = sRList[t];
                int cand = sList[slot] >> 1;
                const float* pc = pos + (size_t)(b * LL + cand) * 45;
                for (int p = lane; p < 225; p += 64) {
                    int a = p / 15, c = p - a * 15;
                    double cx = (double)pc[3*c], cy = (double)pc[3*c+1],
                           cz = (double)pc[3*c+2];
                    double dot = dAi[3*a]*cx + dAi[3*a+1]*cy + dAi[3*a+2]*cz;
                    double d2  = (dX2i[a] + (cx*cx + cy*cy + cz*cz))
                               - 2.0 * dot;
                    dmin = fmin(dmin, d2);
                }
            }
            #pragma unroll
            for (int off = 1; off < 64; off <<= 1)
                dmin = fmin(dmin, __shfl_xor(dmin, off, 64));
            if (lane == 0 && t < rcnt) sVal[slot] = fmax(dmin, 0.0);
        }
    }
    __syncthreads();

    // ---- rank per slot; winners write ordered edge slots ----
    if (j < cnt) {
        int e   = sList[j];
        int cnd = e >> 1, mycls = e & 1;
        double key = sVal[j];
        int r = 0;
        for (int u = 0; u < cnt; ++u) {
            int eu = sList[u];
            if ((eu & 1) == mycls) {
                double ku = sVal[u];
                int cu = eu >> 1;
                if (ku < key || (ku == key && cu < cnd)) ++r;
            }
        }
        if (r < KK) {
            int eo = (mycls == 0 ? 0 : NE_HALF) + blk * KK + r;
            out[O_EDGES + eo]      = (float)blk;            // src
            out[O_EDGES + NE + eo] = (float)(b * LL + cnd); // dst
        }
    }
}

extern "C" void kernel_launch(void* const* d_in, const int* in_sizes, int n_in,
                              void* d_out, int out_size, void* d_ws, size_t ws_size,
                              hipStream_t stream) {
    const float* pos  = (const float*)d_in[0];   // pos_heavyatom [8,256,15,3] f32
    const int*   frag = (const int*)d_in[6];     // fragment_type [8,256] i32
    const float* emb  = (const float*)d_in[7];   // edge_emb [2,16] f32
    float* out = (float*)d_out;
    float* Dm  = (float*)d_ws;                   // [8,256,256] f32 = 2 MB

    dist_kernel<<<dim3(BB * NTILE), dim3(256), 0, stream>>>(pos, Dm);
    select_kernel<<<dim3(BB * LL), dim3(256), 0, stream>>>(pos, Dm, frag,
                                                           emb, out);
}